// Round 3
// baseline (172.562 us; speedup 1.0000x reference)
//
#include <hip/hip_runtime.h>
#include <math.h>

#define BATCH 16
#define S_LEN 4096
#define D2c   256
#define D8c   1024
#define GNUM  24
#define QNUM  48
#define WINc  12
#define NCA   64    // att chunks per batch (64 rows each)
#define NCM   16    // mod blocks per batch (256 rows each, 4 sub-slots of 64)
#define NSLOT 64    // partial slots per batch (att: NCA, mod: NCM*4)

__device__ inline float4 f4max(float4 a, float4 b) {
    return make_float4(fmaxf(a.x,b.x), fmaxf(a.y,b.y), fmaxf(a.z,b.z), fmaxf(a.w,b.w));
}
__device__ inline float4 f4add(float4 a, float4 b) {
    return make_float4(a.x+b.x, a.y+b.y, a.z+b.z, a.w+b.w);
}
__device__ inline float dot4(float4 a, float4 b) {
    return a.x*b.x + a.y*b.y + a.z*b.z + a.w*b.w;
}

// Small LDS footprint is critical: every block in the fused kernel allocates
// this union, and blocks/CU = 160KB / sizeof(ShU). Keep it < ~20KB so the
// streaming blocks stay VGPR-limited (7+ blocks/CU), not LDS-limited.
struct BidafSh {                 // ~16.6 KB
    float s[GNUM][QNUM];         // scores; overwritten in-place by sm1
    float sm2[GNUM][QNUM];
    float v[GNUM][QNUM];
    float m[GNUM][GNUM];
    float s0[GNUM];
    float s1[QNUM];
    float u0[QNUM];
    float u1[QNUM];
    float uc[GNUM];              // dot(c_g, wc_sel(g)[0:D2])
    int   gids[GNUM];
};
struct WinSh {
    float wmf[32];
    float rden;
    float red[256];
};
union ShU { BidafSh bi; WinSh w; };

// ---------------------------------------------------------------------------
// K1: fused bidaf (16) + att partials (1024) + mod partials (256) +
//     per-(b,g>=1) window pooling & partial logit (368).
// ---------------------------------------------------------------------------
__global__ __launch_bounds__(256) void k1_kernel(
    const float* __restrict__ att, const float* __restrict__ mod,
    const float* __restrict__ q_enc,
    const int* __restrict__ gap_idx, const int* __restrict__ mask,
    const int* __restrict__ q_mask,
    const float* __restrict__ c_w, const float* __restrict__ q_w,
    const float* __restrict__ cq_w, const float* __restrict__ att_bias,
    const float* __restrict__ W_att2, const float* __restrict__ W_att_s2,
    const float* __restrict__ W_att, const float* __restrict__ W_mod,
    float* __restrict__ attPmax, float* __restrict__ attPsum,
    float* __restrict__ modPmax, float* __restrict__ modPsum,
    float* __restrict__ att2ws, float* __restrict__ winpart)
{
    __shared__ ShU sh;
    const int tid = threadIdx.x;
    const int bid = blockIdx.x;

    if (bid < BATCH) {
        // ------------------------------ bidaf, b = bid -------------------
        const int b = bid;
        if (tid < GNUM) sh.bi.gids[tid] = gap_idx[b * GNUM + tid];
        __syncthreads();

        // Phase 2: s0, s1, u0, u1, uc (c rows read from global; L2-hot)
        if (tid < GNUM) {
            const float4* cr = reinterpret_cast<const float4*>(
                mod + ((size_t)b * S_LEN + sh.bi.gids[tid]) * D2c);
            const float4* w4 = reinterpret_cast<const float4*>(c_w);
            float a = 0.f;
            for (int d = 0; d < D2c/4; ++d) a += dot4(cr[d], w4[d]);
            sh.bi.s0[tid] = a;
        } else if (tid >= 32 && tid < 32 + QNUM) {
            const int q = tid - 32;
            const float4* qr = reinterpret_cast<const float4*>(q_enc + ((size_t)b*QNUM + q)*D2c);
            const float4* w4 = reinterpret_cast<const float4*>(q_w);
            float a = 0.f;
            for (int d = 0; d < D2c/4; ++d) a += dot4(qr[d], w4[d]);
            sh.bi.s1[q] = a;
        } else if (tid >= 96 && tid < 96 + QNUM) {
            const int q = tid - 96;
            const float4* qr = reinterpret_cast<const float4*>(q_enc + ((size_t)b*QNUM + q)*D2c);
            const float4* w4 = reinterpret_cast<const float4*>(W_att_s2 + D2c);
            float a = 0.f;
            for (int d = 0; d < D2c/4; ++d) a += dot4(qr[d], w4[d]);
            sh.bi.u0[q] = a;
        } else if (tid >= 160 && tid < 160 + QNUM) {
            const int q = tid - 160;
            const float4* qr = reinterpret_cast<const float4*>(q_enc + ((size_t)b*QNUM + q)*D2c);
            const float4* w4 = reinterpret_cast<const float4*>(W_att2 + D2c);
            float a = 0.f;
            for (int d = 0; d < D2c/4; ++d) a += dot4(qr[d], w4[d]);
            sh.bi.u1[q] = a;
        } else if (tid >= 224 && tid < 224 + GNUM) {
            const int g = tid - 224;
            const float4* cr = reinterpret_cast<const float4*>(
                mod + ((size_t)b * S_LEN + sh.bi.gids[g]) * D2c);
            const float4* w4 = reinterpret_cast<const float4*>((g == 0) ? W_att_s2 : W_att2);
            float a = 0.f;
            for (int d = 0; d < D2c/4; ++d) a += dot4(cr[d], w4[d]);
            sh.bi.uc[g] = a;
        }
        __syncthreads();

        // Phase 3: s matrix + v[g][q]
        const float bias = att_bias[0];
        for (int i = tid; i < GNUM * QNUM; i += 256) {
            const int g = i / QNUM, q = i % QNUM;
            const float4* cr  = reinterpret_cast<const float4*>(
                mod + ((size_t)b * S_LEN + sh.bi.gids[g]) * D2c);
            const float4* qr  = reinterpret_cast<const float4*>(q_enc + ((size_t)b*QNUM + q)*D2c);
            const float4* cw  = reinterpret_cast<const float4*>(cq_w);
            const float4* wca = reinterpret_cast<const float4*>(((g == 0) ? W_att_s2 : W_att2) + 2*D2c);
            float s2 = 0.f, vv = 0.f;
            for (int d = 0; d < D2c/4; ++d) {
                const float4 cc = cr[d], qq = qr[d];
                const float4 cq = make_float4(cc.x*qq.x, cc.y*qq.y, cc.z*qq.z, cc.w*qq.w);
                s2 += dot4(cq, cw[d]);
                vv += dot4(cq, wca[d]);
            }
            sh.bi.s[g][q] = sh.bi.s0[g] + sh.bi.s1[q] + s2 + bias;
            sh.bi.v[g][q] = vv;
        }
        __syncthreads();

        // Phase 4a: sm2 (softmax over g, reads s)
        if (tid >= 64 && tid < 64 + QNUM) {
            const int q = tid - 64;
            float mxv = -1e30f;
            for (int g = 0; g < GNUM; ++g) mxv = fmaxf(mxv, sh.bi.s[g][q]);
            float sum = 0.f;
            for (int g = 0; g < GNUM; ++g) {
                const float e = __expf(sh.bi.s[g][q] - mxv);
                sh.bi.sm2[g][q] = e;
                sum += e;
            }
            const float inv = 1.f / sum;
            for (int g = 0; g < GNUM; ++g) sh.bi.sm2[g][q] *= inv;
        }
        __syncthreads();

        // Phase 4b: sm1 overwrites s in place (row-local)
        if (tid < GNUM) {
            const int g = tid;
            float mxv = -1e30f;
            for (int q = 0; q < QNUM; ++q)
                if (q_mask[b*QNUM + q]) mxv = fmaxf(mxv, sh.bi.s[g][q]);
            float sum = 0.f;
            for (int q = 0; q < QNUM; ++q) {
                const float e = q_mask[b*QNUM + q] ? __expf(sh.bi.s[g][q] - mxv) : 0.f;
                sum += e;
            }
            const float inv = 1.f / sum;
            for (int q = 0; q < QNUM; ++q) {
                const float e = q_mask[b*QNUM + q] ? __expf(sh.bi.s[g][q] - mxv) : 0.f;
                sh.bi.s[g][q] = e * inv;
            }
        }
        __syncthreads();

        // Phase 5: m[g][k] = sum_d c_g[d]*c_k[d]*wcb_sel(g)[d]
        for (int i = tid; i < GNUM * GNUM; i += 256) {
            const int g = i / GNUM, k = i % GNUM;
            const float4* cg = reinterpret_cast<const float4*>(
                mod + ((size_t)b * S_LEN + sh.bi.gids[g]) * D2c);
            const float4* ck = reinterpret_cast<const float4*>(
                mod + ((size_t)b * S_LEN + sh.bi.gids[k]) * D2c);
            const float4* wcb = reinterpret_cast<const float4*>(((g == 0) ? W_att_s2 : W_att2) + 3*D2c);
            float a = 0.f;
            for (int d = 0; d < D2c/4; ++d) {
                const float4 x = cg[d], y = ck[d], w = wcb[d];
                a += x.x*y.x*w.x + x.y*y.y*w.y + x.z*y.z*w.z + x.w*y.w*w.w;
            }
            sh.bi.m[g][k] = a;
        }
        __syncthreads();

        // Phase 6: att2 logit per g (s now holds sm1)
        if (tid < GNUM) {
            const int g = tid;
            const float* uu = (g == 0) ? sh.bi.u0 : sh.bi.u1;
            float acc = sh.bi.uc[g];
            for (int q = 0; q < QNUM; ++q) acc += sh.bi.s[g][q] * (uu[q] + sh.bi.v[g][q]);
            for (int k = 0; k < GNUM; ++k) {
                float ss = 0.f;
                for (int q = 0; q < QNUM; ++q) ss += sh.bi.s[g][q] * sh.bi.sm2[k][q];
                acc += ss * sh.bi.m[g][k];
            }
            att2ws[b * GNUM + g] = acc;
        }
    } else if (bid < BATCH + BATCH*NCA) {
        // ------------------------------ att partials ---------------------
        const int ab = bid - BATCH;
        const int b = ab >> 6, ch = ab & 63;
        const float4* base = reinterpret_cast<const float4*>(att)
                             + ((size_t)b * S_LEN + ch * 64) * (D8c/4) + tid;
        float4 mx = make_float4(-INFINITY, -INFINITY, -INFINITY, -INFINITY);
        float4 sm = make_float4(0.f, 0.f, 0.f, 0.f);
        #pragma unroll 8
        for (int r = 0; r < 64; ++r) {
            const float4 v = base[(size_t)r * (D8c/4)];
            mx = f4max(mx, v);
            sm = f4add(sm, v);
        }
        reinterpret_cast<float4*>(attPmax)[(size_t)ab * (D8c/4) + tid] = mx;
        reinterpret_cast<float4*>(attPsum)[(size_t)ab * (D8c/4) + tid] = sm;
    } else if (bid < BATCH + BATCH*NCA + BATCH*NCM) {
        // ------------------------------ mod partials ---------------------
        const int mb = bid - BATCH - BATCH*NCA;
        const int b = mb >> 4, ch = mb & 15;
        const int rg = tid >> 6, c4 = tid & 63;
        const float4* base = reinterpret_cast<const float4*>(mod)
                             + ((size_t)b * S_LEN + ch * 256 + rg * 64) * (D2c/4) + c4;
        float4 mx = make_float4(-INFINITY, -INFINITY, -INFINITY, -INFINITY);
        float4 sm = make_float4(0.f, 0.f, 0.f, 0.f);
        #pragma unroll 8
        for (int r = 0; r < 64; ++r) {
            const float4 v = base[(size_t)r * (D2c/4)];
            mx = f4max(mx, v);
            sm = f4add(sm, v);
        }
        const int slot = (b * NCM + ch) * 4 + rg;   // = b*64 + ch*4 + rg
        reinterpret_cast<float4*>(modPmax)[(size_t)slot * (D2c/4) + c4] = mx;
        reinterpret_cast<float4*>(modPsum)[(size_t)slot * (D2c/4) + c4] = sm;
    } else {
        // ------------------------------ window blocks (g>=1) -------------
        const int wb = bid - BATCH - BATCH*NCA - BATCH*NCM;
        const int b = wb / (GNUM - 1), g = wb % (GNUM - 1) + 1;
        const int gid = gap_idx[b * GNUM + g];
        const int lo = (gid - WINc > 0) ? gid - WINc : 0;
        const int hi = (gid + WINc < S_LEN - 1) ? gid + WINc : S_LEN - 1;
        const int n = hi - lo + 1;

        if (tid < n) sh.w.wmf[tid] = (mask[b * S_LEN + lo + tid] != 0) ? 1.f : 0.f;
        __syncthreads();
        if (tid == 0) {
            float d = 0.f;
            for (int i = 0; i < n; ++i) d += sh.w.wmf[i];
            sh.w.rden = 1.f / d;
        }
        __syncthreads();
        const float rden = sh.w.rden;

        const float4* Wa4 = reinterpret_cast<const float4*>(W_att);
        const float4* Wm4 = reinterpret_cast<const float4*>(W_mod);

        float acc = 0.f;
        {
            const float4* base = reinterpret_cast<const float4*>(att)
                                 + ((size_t)b * S_LEN + lo) * (D8c/4) + tid;
            float4 mx = make_float4(0.f, 0.f, 0.f, 0.f);  // max clamped at 0 (zeros outside window)
            float4 sm = make_float4(0.f, 0.f, 0.f, 0.f);
            for (int i = 0; i < n; ++i) {
                if (sh.w.wmf[i] != 0.f) {
                    const float4 v = base[(size_t)i * (D8c/4)];
                    mx = f4max(mx, v);
                    sm = f4add(sm, v);
                }
            }
            acc += dot4(mx, Wa4[(D8c/4) + tid]) + dot4(sm, Wa4[2*(D8c/4) + tid]) * rden;
            const float4 ar = reinterpret_cast<const float4*>(att)[((size_t)b * S_LEN + gid) * (D8c/4) + tid];
            acc += dot4(ar, Wa4[tid]);
        }
        if (tid < D2c/4) {
            const float4* base = reinterpret_cast<const float4*>(mod)
                                 + ((size_t)b * S_LEN + lo) * (D2c/4) + tid;
            float4 mx = make_float4(0.f, 0.f, 0.f, 0.f);
            float4 sm = make_float4(0.f, 0.f, 0.f, 0.f);
            for (int i = 0; i < n; ++i) {
                if (sh.w.wmf[i] != 0.f) {
                    const float4 v = base[(size_t)i * (D2c/4)];
                    mx = f4max(mx, v);
                    sm = f4add(sm, v);
                }
            }
            acc += dot4(mx, Wm4[(D2c/4) + tid]) + dot4(sm, Wm4[2*(D2c/4) + tid]) * rden;
            const float4 mr = reinterpret_cast<const float4*>(mod)[((size_t)b * S_LEN + gid) * (D2c/4) + tid];
            acc += dot4(mr, Wm4[tid]);
        }

        sh.w.red[tid] = acc;
        __syncthreads();
        for (int off = 128; off > 0; off >>= 1) {
            if (tid < off) sh.w.red[tid] += sh.w.red[tid + off];
            __syncthreads();
        }
        if (tid == 0) winpart[b * GNUM + g] = sh.w.red[0];
    }
}

// ---------------------------------------------------------------------------
// K2: per-batch g==0 combine + final output assembly. 16 blocks.
// ---------------------------------------------------------------------------
__global__ __launch_bounds__(256) void k2_kernel(
    const float* __restrict__ att, const float* __restrict__ mod,
    const int* __restrict__ gap_idx, const int* __restrict__ mask,
    const float* __restrict__ W_att_s, const float* __restrict__ W_mod_s,
    const float* __restrict__ b_att, const float* __restrict__ b_mod,
    const float* __restrict__ b_att2,
    const float* __restrict__ b_att_s, const float* __restrict__ b_mod_s,
    const float* __restrict__ b_att_s2,
    const float* __restrict__ attPmax, const float* __restrict__ attPsum,
    const float* __restrict__ modPmax, const float* __restrict__ modPsum,
    const float* __restrict__ att2ws, const float* __restrict__ winpart,
    float* __restrict__ out)
{
    const int b = blockIdx.x;
    const int tid = threadIdx.x;
    __shared__ float red[256];
    __shared__ float rdensh;

    // denom0 = sum(mask[b,:])
    float cnt = 0.f;
    for (int s = tid; s < S_LEN; s += 256) cnt += (mask[b * S_LEN + s] != 0) ? 1.f : 0.f;
    red[tid] = cnt;
    __syncthreads();
    for (int off = 128; off > 0; off >>= 1) {
        if (tid < off) red[tid] += red[tid + off];
        __syncthreads();
    }
    if (tid == 0) rdensh = 1.f / red[0];
    __syncthreads();
    const float rden0 = rdensh;

    const int gid0 = gap_idx[b * GNUM];
    const float4* Wa4 = reinterpret_cast<const float4*>(W_att_s);
    const float4* Wm4 = reinterpret_cast<const float4*>(W_mod_s);

    float acc = 0.f;
    {
        float4 mx = make_float4(-INFINITY, -INFINITY, -INFINITY, -INFINITY);
        float4 sm = make_float4(0.f, 0.f, 0.f, 0.f);
        #pragma unroll 8
        for (int ch = 0; ch < NSLOT; ++ch) {
            const size_t idx = ((size_t)b * NSLOT + ch) * (D8c/4) + tid;
            mx = f4max(mx, reinterpret_cast<const float4*>(attPmax)[idx]);
            sm = f4add(sm, reinterpret_cast<const float4*>(attPsum)[idx]);
        }
        acc += dot4(mx, Wa4[(D8c/4) + tid]) + dot4(sm, Wa4[2*(D8c/4) + tid]) * rden0;
        const float4 ar = reinterpret_cast<const float4*>(att)[((size_t)b * S_LEN + gid0) * (D8c/4) + tid];
        acc += dot4(ar, Wa4[tid]);
    }
    if (tid < D2c/4) {
        float4 mx = make_float4(-INFINITY, -INFINITY, -INFINITY, -INFINITY);
        float4 sm = make_float4(0.f, 0.f, 0.f, 0.f);
        #pragma unroll 8
        for (int ch = 0; ch < NSLOT; ++ch) {
            const size_t idx = ((size_t)b * NSLOT + ch) * (D2c/4) + tid;
            mx = f4max(mx, reinterpret_cast<const float4*>(modPmax)[idx]);
            sm = f4add(sm, reinterpret_cast<const float4*>(modPsum)[idx]);
        }
        acc += dot4(mx, Wm4[(D2c/4) + tid]) + dot4(sm, Wm4[2*(D2c/4) + tid]) * rden0;
        const float4 mr = reinterpret_cast<const float4*>(mod)[((size_t)b * S_LEN + gid0) * (D2c/4) + tid];
        acc += dot4(mr, Wm4[tid]);
    }

    __syncthreads();
    red[tid] = acc;
    __syncthreads();
    for (int off = 128; off > 0; off >>= 1) {
        if (tid < off) red[tid] += red[tid + off];
        __syncthreads();
    }
    if (tid == 0) {
        out[b * GNUM] = red[0] + att2ws[b * GNUM] + b_att_s[0] + b_mod_s[0] + b_att_s2[0];
    } else if (tid < GNUM) {
        out[b * GNUM + tid] = winpart[b * GNUM + tid] + att2ws[b * GNUM + tid]
                              + b_att[0] + b_mod[0] + b_att2[0];
    }
}

// ---------------------------------------------------------------------------
extern "C" void kernel_launch(void* const* d_in, const int* in_sizes, int n_in,
                              void* d_out, int out_size, void* d_ws, size_t ws_size,
                              hipStream_t stream)
{
    const float* att      = (const float*)d_in[0];
    const float* mod      = (const float*)d_in[1];
    const float* q_enc    = (const float*)d_in[2];
    const int*   gap_idx  = (const int*)  d_in[3];
    const int*   mask     = (const int*)  d_in[4];
    const int*   q_mask   = (const int*)  d_in[5];
    const float* c_w      = (const float*)d_in[6];
    const float* q_w      = (const float*)d_in[7];
    const float* cq_w     = (const float*)d_in[8];
    const float* att_bias = (const float*)d_in[9];
    const float* W_att    = (const float*)d_in[10];
    const float* b_att    = (const float*)d_in[11];
    const float* W_mod    = (const float*)d_in[12];
    const float* b_mod    = (const float*)d_in[13];
    const float* W_att2   = (const float*)d_in[14];
    const float* b_att2   = (const float*)d_in[15];
    const float* W_att_s  = (const float*)d_in[16];
    const float* b_att_s  = (const float*)d_in[17];
    const float* W_mod_s  = (const float*)d_in[18];
    const float* b_mod_s  = (const float*)d_in[19];
    const float* W_att_s2 = (const float*)d_in[20];
    const float* b_att_s2 = (const float*)d_in[21];

    float* out = (float*)d_out;

    float* ws = (float*)d_ws;
    float* attPmax = ws;                                            // 16*64*1024
    float* attPsum = attPmax + (size_t)BATCH * NSLOT * D8c;
    float* modPmax = attPsum + (size_t)BATCH * NSLOT * D8c;         // 16*64*256
    float* modPsum = modPmax + (size_t)BATCH * NSLOT * D2c;
    float* att2ws  = modPsum + (size_t)BATCH * NSLOT * D2c;         // 384
    float* winpart = att2ws  + (size_t)BATCH * GNUM;                // 384

    const int grid1 = BATCH + BATCH*NCA + BATCH*NCM + BATCH*(GNUM-1);

    k1_kernel<<<grid1, 256, 0, stream>>>(
        att, mod, q_enc, gap_idx, mask, q_mask,
        c_w, q_w, cq_w, att_bias, W_att2, W_att_s2, W_att, W_mod,
        attPmax, attPsum, modPmax, modPsum, att2ws, winpart);

    k2_kernel<<<BATCH, 256, 0, stream>>>(
        att, mod, gap_idx, mask, W_att_s, W_mod_s,
        b_att, b_mod, b_att2, b_att_s, b_mod_s, b_att_s2,
        attPmax, attPsum, modPmax, modPsum, att2ws, winpart, out);
}